// Round 3
// baseline (440.889 us; speedup 1.0000x reference)
//
#include <hip/hip_runtime.h>
#include <hip/hip_bf16.h>

#define HSIZE   (1 << 20)
#define HMASK   (HSIZE - 1)
#define PAIR_CAP (1 << 18)
#define HEMPTY  0xFFFFFFFFFFFFFFFFULL

typedef __bf16 bf16_t;
typedef bf16_t bf16x8 __attribute__((ext_vector_type(8)));
typedef float  f32x4  __attribute__((ext_vector_type(4)));
typedef unsigned long long u64;

__device__ __forceinline__ unsigned hash_key(int k) {
    return ((unsigned)k * 2654435761u) >> 12;   // top 20 bits -> [0, 2^20)
}

// K1: pack keys + 4096-bucket histogram; tail blocks pre-pack W[13] into B-frag order.
__global__ void k_phase1(const int* __restrict__ coords, const float* __restrict__ kern,
                         int* __restrict__ keys, int* __restrict__ hist,
                         bf16_t* __restrict__ wf, int N, int nb) {
    if (blockIdx.x >= nb) {
        // frag f = nt*2+kt; elem (lane l, j) = B[k][n], k=kt*32+(l>>4)*8+j, n=nt*16+(l&15)
        int tid = (blockIdx.x - nb) * 256 + threadIdx.x;   // 0..4095
        int f = tid >> 9, l = (tid >> 3) & 63, j = tid & 7;
        int nt = f >> 1, kt = f & 1;
        int k = kt * 32 + ((l >> 4) * 8) + j;
        int n = nt * 16 + (l & 15);
        wf[tid] = (bf16_t)kern[13 * 4096 + k * 64 + n];
        return;
    }
    int i = blockIdx.x * 256 + threadIdx.x;
    if (i >= N) return;
    int key = (coords[3 * i] << 20) | (coords[3 * i + 1] << 10) | coords[3 * i + 2];
    keys[i] = key;
    atomicAdd(&hist[key >> 18], 1);
}

// K2: exclusive prefix over 4096 buckets — wave-shuffle scan, 1 block.
__global__ void k_prefix(const int* __restrict__ hist, int* __restrict__ base) {
    int t = threadIdx.x;
    int vals[16];
    int s = 0;
#pragma unroll
    for (int j = 0; j < 16; ++j) { vals[j] = hist[t * 16 + j]; s += vals[j]; }
    int lane = t & 63, wv = t >> 6;
    int x = s;
#pragma unroll
    for (int d = 1; d < 64; d <<= 1) {
        int y = __shfl_up(x, d, 64);
        if (lane >= d) x += y;
    }
    __shared__ int wsum[4];
    if (lane == 63) wsum[wv] = x;
    __syncthreads();
    int add = 0;
    for (int u = 0; u < wv; ++u) add += wsum[u];
    int run = (x + add) - s;                 // exclusive prefix of this thread's segment
#pragma unroll
    for (int j = 0; j < 16; ++j) { base[t * 16 + j] = run; run += vals[j]; }
    if (t == 255) base[4096] = x + add;      // == N
}

// K3: bucket scatter (packed 8B) + 64-bit hash insert. One 8B store + one 8B CAS per point.
__global__ void k_build(const int* __restrict__ keys, const int* __restrict__ base,
                        int* __restrict__ cnt, u64* __restrict__ sortbuf,
                        u64* __restrict__ htab, int N) {
    int i = blockIdx.x * 256 + threadIdx.x;
    if (i >= N) return;
    int key = keys[i];
    int b = key >> 18;
    int pos = base[b] + atomicAdd(&cnt[b], 1);
    sortbuf[pos] = ((u64)(unsigned)key << 20) | (unsigned)i;   // key(30b) | orig(20b)
    u64 entry = ((u64)(unsigned)key << 32) | (unsigned)i;
    unsigned slot = hash_key(key);
    while (atomicCAS(&htab[slot], HEMPTY, entry) != HEMPTY)
        slot = (slot + 1) & HMASK;
}

// K4: per-bucket rank sort -> rank_ (orig idx -> sorted pos). Keys unique.
__global__ void k_sortrank(const int* __restrict__ base, const u64* __restrict__ sortbuf,
                           int* __restrict__ rank_) {
    int b = blockIdx.x;
    int lo = base[b], hi = base[b + 1];
    int size = hi - lo;
    if (size <= 0) return;
    __shared__ u64 sk[512];                  // mean bucket ~98; P(>512) ~ 0
    for (int e = threadIdx.x; e < size && e < 512; e += 256) sk[e] = sortbuf[lo + e];
    __syncthreads();
    for (int e = threadIdx.x; e < size; e += 256) {
        u64 my = (e < 512) ? sk[e] : sortbuf[lo + e];
        int r = 0;
        for (int j = 0; j < size; ++j) {
            u64 kj = (j < 512) ? sk[j] : sortbuf[lo + j];
            r += (kj < my);
        }
        rank_[(int)(my & 0xFFFFF)] = lo + r;
    }
}

// K5: dense center GEMM, STREAMING reads (orig order), scatter writes via rank_.
// out[rank_[i]] = F[i] @ W13.  MFMA 16x16x32 bf16, no LDS, no gather waits.
__global__ __launch_bounds__(256) void k_gemm(const float* __restrict__ feat,
                                              const bf16_t* __restrict__ wf,
                                              const int* __restrict__ rank_,
                                              float* __restrict__ out, int N) {
    const int lane = threadIdx.x & 63;
    const int wv = threadIdx.x >> 6;
    const int m = lane & 15, quad = lane >> 4;
    const int tile = blockIdx.x * 64 + wv * 16;
    int row = tile + m;
    if (row >= N) row = N - 1;
    const float* rp = feat + (size_t)row * 64;
    bf16x8 a[2];
#pragma unroll
    for (int kt = 0; kt < 2; ++kt) {
        const float* p = rp + kt * 32 + quad * 8;
        float4 x = *(const float4*)p;
        float4 y = *(const float4*)(p + 4);
        bf16x8 v;
        v[0] = (bf16_t)x.x; v[1] = (bf16_t)x.y; v[2] = (bf16_t)x.z; v[3] = (bf16_t)x.w;
        v[4] = (bf16_t)y.x; v[5] = (bf16_t)y.y; v[6] = (bf16_t)y.z; v[7] = (bf16_t)y.w;
        a[kt] = v;
    }
    // destination rows (16 per wave, broadcast loads within each quad-group)
    int orow[4];
#pragma unroll
    for (int r = 0; r < 4; ++r) {
        int srow = tile + quad * 4 + r;
        orow[r] = (srow < N) ? rank_[srow] : -1;
    }
#pragma unroll
    for (int nt = 0; nt < 4; ++nt) {
        f32x4 acc = {0.f, 0.f, 0.f, 0.f};
#pragma unroll
        for (int kt = 0; kt < 2; ++kt) {
            bf16x8 bfr = *(const bf16x8*)(wf + ((nt * 2 + kt) * 64 + lane) * 8);
            acc = __builtin_amdgcn_mfma_f32_16x16x32_bf16(a[kt], bfr, acc, 0, 0, 0);
        }
#pragma unroll
        for (int r = 0; r < 4; ++r)
            if (orow[r] >= 0) out[(size_t)orow[r] * 64 + nt * 16 + m] = acc[r];
    }
}

// K6: one thread per point; 13 independent first-probe 8B loads (key+val in one).
__global__ void k_query(const int* __restrict__ keys, const int* __restrict__ rank_,
                        const int* __restrict__ offs, const u64* __restrict__ htab,
                        int* __restrict__ paircnt, int* __restrict__ pairs, int N) {
    int i = blockIdx.x * 256 + threadIdx.x;
    if (i >= N) return;
    int mykey = keys[i];
    int qk[13];
    u64 ent[13];
#pragma unroll
    for (int k = 0; k < 13; ++k) {
        int okey = offs[3 * k] * 1048576 + offs[3 * k + 1] * 1024 + offs[3 * k + 2];
        qk[k] = mykey + okey;
    }
#pragma unroll
    for (int k = 0; k < 13; ++k)
        ent[k] = htab[hash_key(qk[k])];      // independent -> overlapped in flight
#pragma unroll
    for (int k = 0; k < 13; ++k) {
        int j = -1;
        u64 e = ent[k];
        if (e != HEMPTY) {
            if ((int)(e >> 32) == qk[k]) {
                j = (int)(e & 0xFFFFFFFFu);
            } else {                          // rare: continue the probe chain
                unsigned slot = (hash_key(qk[k]) + 1) & HMASK;
                for (;;) {
                    u64 t = htab[slot];
                    if (t == HEMPTY) break;
                    if ((int)(t >> 32) == qk[k]) { j = (int)(t & 0xFFFFFFFFu); break; }
                    slot = (slot + 1) & HMASK;
                }
            }
        }
        if (j >= 0) {
            int idx = atomicAdd(paircnt, 2);
            if (idx + 1 < PAIR_CAP) {
                // out[rank(i)] += F[j] @ W[k];  out[rank(j)] += F[i] @ W[26-k]
                pairs[3 * idx + 0] = rank_[i];
                pairs[3 * idx + 1] = j;
                pairs[3 * idx + 2] = k;
                pairs[3 * idx + 3] = rank_[j];
                pairs[3 * idx + 4] = i;
                pairs[3 * idx + 5] = 26 - k;
            }
        }
    }
}

// K7: sparse pairs — one wave per pair, fp32 shuffle-dot, atomic accumulate.
__global__ void k_pairs(const float* __restrict__ feat, const float* __restrict__ kern,
                        const int* __restrict__ pairs, const int* __restrict__ paircnt,
                        float* __restrict__ out) {
    int gtid = blockIdx.x * blockDim.x + threadIdx.x;
    int wid = gtid >> 6, lane = gtid & 63;
    int nw = (gridDim.x * blockDim.x) >> 6;
    int cnt = *paircnt;
    if (cnt > PAIR_CAP) cnt = PAIR_CAP;
    for (int p = wid; p < cnt; p += nw) {
        int dst = pairs[3 * p], src = pairs[3 * p + 1], wk = pairs[3 * p + 2];
        float f = feat[(size_t)src * 64 + lane];
        const float* W = kern + wk * 4096;
        float acc = 0.f;
#pragma unroll
        for (int c = 0; c < 64; ++c)
            acc += __shfl(f, c, 64) * W[c * 64 + lane];
        atomicAdd(&out[(size_t)dst * 64 + lane], acc);
    }
}

extern "C" void kernel_launch(void* const* d_in, const int* in_sizes, int n_in,
                              void* d_out, int out_size, void* d_ws, size_t ws_size,
                              hipStream_t stream) {
    const float* feat   = (const float*)d_in[0];
    const float* kern   = (const float*)d_in[1];
    const int*   coords = (const int*)d_in[2];
    const int*   offs   = (const int*)d_in[3];
    float* out = (float*)d_out;
    int N = in_sizes[0] / 64;

    // ---- workspace layout (256B-aligned slabs) ----
    char* w = (char*)d_ws;
    auto alloc = [&](size_t bytes) { char* p = w; w += (bytes + 255) & ~(size_t)255; return p; };
    int* keys    = (int*)alloc((size_t)N * 4);
    u64* sortbuf = (u64*)alloc((size_t)N * 8);
    int* rank_   = (int*)alloc((size_t)N * 4);
    int* hist    = (int*)alloc(4096 * 4);        // contiguous: hist, cnt, paircnt
    int* cnt     = (int*)alloc(4096 * 4);
    int* paircnt = (int*)alloc(256);
    int* base    = (int*)alloc(4097 * 4);
    u64* htab    = (u64*)alloc((size_t)HSIZE * 8);
    int* pairs   = (int*)alloc((size_t)PAIR_CAP * 12);
    bf16_t* wf   = (bf16_t*)alloc(4096 * 2);

    // zero hist+cnt+paircnt (contiguous slabs); hash entries -> all-ones (empty)
    hipMemsetAsync(hist, 0, 4096 * 4 + 4096 * 4 + 256, stream);
    hipMemsetAsync(htab, 0xFF, (size_t)HSIZE * 8, stream);

    int nb = (N + 255) / 256;
    k_phase1  <<<nb + 16, 256, 0, stream>>>(coords, kern, keys, hist, wf, N, nb);
    k_prefix  <<<1, 256, 0, stream>>>(hist, base);
    k_build   <<<nb, 256, 0, stream>>>(keys, base, cnt, sortbuf, htab, N);
    k_sortrank<<<4096, 256, 0, stream>>>(base, sortbuf, rank_);
    k_gemm    <<<(N + 63) / 64, 256, 0, stream>>>(feat, wf, rank_, out, N);
    k_query   <<<nb, 256, 0, stream>>>(keys, rank_, offs, htab, paircnt, pairs, N);
    k_pairs   <<<256, 256, 0, stream>>>(feat, kern, pairs, paircnt, out);
}

// Round 4
// 352.936 us; speedup vs baseline: 1.2492x; 1.2492x over previous
//
#include <hip/hip_runtime.h>
#include <hip/hip_bf16.h>

#define PAIR_CAP (1 << 18)
#define QCHUNK   1024
#define WPAD     3072
#define WCAP     (QCHUNK + 2 * WPAD + 128)   // 7296 ints = 29.2 KB LDS

typedef __bf16 bf16_t;
typedef bf16_t bf16x8 __attribute__((ext_vector_type(8)));
typedef float  f32x4  __attribute__((ext_vector_type(4)));
typedef unsigned long long u64;

// K1: pack keys + 4096-bucket histogram; tail blocks pre-pack W[13] into B-frag order.
__global__ void k_phase1(const int* __restrict__ coords, const float* __restrict__ kern,
                         int* __restrict__ keys, int* __restrict__ hist,
                         bf16_t* __restrict__ wf, int N, int nb) {
    if (blockIdx.x >= nb) {
        // frag f = nt*2+kt; elem (lane l, j) = B[k][n], k=kt*32+(l>>4)*8+j, n=nt*16+(l&15)
        int tid = (blockIdx.x - nb) * 256 + threadIdx.x;   // 0..4095
        int f = tid >> 9, l = (tid >> 3) & 63, j = tid & 7;
        int nt = f >> 1, kt = f & 1;
        int k = kt * 32 + ((l >> 4) * 8) + j;
        int n = nt * 16 + (l & 15);
        wf[tid] = (bf16_t)kern[13 * 4096 + k * 64 + n];
        return;
    }
    int i = blockIdx.x * 256 + threadIdx.x;
    if (i >= N) return;
    int key = (coords[3 * i] << 20) | (coords[3 * i + 1] << 10) | coords[3 * i + 2];
    keys[i] = key;
    atomicAdd(&hist[key >> 18], 1);
}

// K2: exclusive prefix over 4096 buckets — wave-shuffle scan, 1 block.
__global__ void k_prefix(const int* __restrict__ hist, int* __restrict__ base) {
    int t = threadIdx.x;
    int vals[16];
    int s = 0;
#pragma unroll
    for (int j = 0; j < 16; ++j) { vals[j] = hist[t * 16 + j]; s += vals[j]; }
    int lane = t & 63, wv = t >> 6;
    int x = s;
#pragma unroll
    for (int d = 1; d < 64; d <<= 1) {
        int y = __shfl_up(x, d, 64);
        if (lane >= d) x += y;
    }
    __shared__ int wsum[4];
    if (lane == 63) wsum[wv] = x;
    __syncthreads();
    int add = 0;
    for (int u = 0; u < wv; ++u) add += wsum[u];
    int run = (x + add) - s;                 // exclusive prefix of this thread's segment
#pragma unroll
    for (int j = 0; j < 16; ++j) { base[t * 16 + j] = run; run += vals[j]; }
    if (t == 255) base[4096] = x + add;      // == N
}

// K3: bucket scatter only — one packed 8B store per point. (Hash table eliminated.)
__global__ void k_build(const int* __restrict__ keys, const int* __restrict__ base,
                        int* __restrict__ cnt, u64* __restrict__ sortbuf, int N) {
    int i = blockIdx.x * 256 + threadIdx.x;
    if (i >= N) return;
    int key = keys[i];
    int b = key >> 18;
    int pos = base[b] + atomicAdd(&cnt[b], 1);
    sortbuf[pos] = ((u64)(unsigned)key << 20) | (unsigned)i;   // key(30b) | orig(<2^19)
}

// K4: per-bucket rank sort -> skeys (sorted keys), sorder (pos->orig), rank_ (orig->pos).
__global__ void k_sortrank(const int* __restrict__ base, const u64* __restrict__ sortbuf,
                           int* __restrict__ skeys, int* __restrict__ sorder,
                           int* __restrict__ rank_) {
    int b = blockIdx.x;
    int lo = base[b], hi = base[b + 1];
    int size = hi - lo;
    if (size <= 0) return;
    __shared__ u64 sk[512];                  // mean bucket ~98; P(>512) ~ 0
    for (int e = threadIdx.x; e < size && e < 512; e += 256) sk[e] = sortbuf[lo + e];
    __syncthreads();
    for (int e = threadIdx.x; e < size; e += 256) {
        u64 my = (e < 512) ? sk[e] : sortbuf[lo + e];
        int r = 0;
        for (int j = 0; j < size; ++j) {
            u64 kj = (j < 512) ? sk[j] : sortbuf[lo + j];
            r += (kj < my);
        }
        int o = (int)(my & 0xFFFFF);
        skeys[lo + r]  = (int)(my >> 20);
        sorder[lo + r] = o;
        rank_[o] = lo + r;
    }
}

// K5: dense center GEMM, STREAMING reads (orig order), scatter writes via rank_.
__global__ __launch_bounds__(256) void k_gemm(const float* __restrict__ feat,
                                              const bf16_t* __restrict__ wf,
                                              const int* __restrict__ rank_,
                                              float* __restrict__ out, int N) {
    const int lane = threadIdx.x & 63;
    const int wv = threadIdx.x >> 6;
    const int m = lane & 15, quad = lane >> 4;
    const int tile = blockIdx.x * 64 + wv * 16;
    int row = tile + m;
    if (row >= N) row = N - 1;
    const float* rp = feat + (size_t)row * 64;
    bf16x8 a[2];
#pragma unroll
    for (int kt = 0; kt < 2; ++kt) {
        const float* p = rp + kt * 32 + quad * 8;
        float4 x = *(const float4*)p;
        float4 y = *(const float4*)(p + 4);
        bf16x8 v;
        v[0] = (bf16_t)x.x; v[1] = (bf16_t)x.y; v[2] = (bf16_t)x.z; v[3] = (bf16_t)x.w;
        v[4] = (bf16_t)y.x; v[5] = (bf16_t)y.y; v[6] = (bf16_t)y.z; v[7] = (bf16_t)y.w;
        a[kt] = v;
    }
    int orow[4];
#pragma unroll
    for (int r = 0; r < 4; ++r) {
        int srow = tile + quad * 4 + r;
        orow[r] = (srow < N) ? rank_[srow] : -1;
    }
#pragma unroll
    for (int nt = 0; nt < 4; ++nt) {
        f32x4 acc = {0.f, 0.f, 0.f, 0.f};
#pragma unroll
        for (int kt = 0; kt < 2; ++kt) {
            bf16x8 bfr = *(const bf16x8*)(wf + ((nt * 2 + kt) * 64 + lane) * 8);
            acc = __builtin_amdgcn_mfma_f32_16x16x32_bf16(a[kt], bfr, acc, 0, 0, 0);
        }
#pragma unroll
        for (int r = 0; r < 4; ++r)
            if (orow[r] >= 0) out[(size_t)orow[r] * 64 + nt * 16 + m] = acc[r];
    }
}

__device__ __forceinline__ int lower_bound_g(const int* __restrict__ a, int n, int q) {
    int lo = 0, hi = n;
    while (lo < hi) { int mid = (lo + hi) >> 1; if (a[mid] < q) lo = mid + 1; else hi = mid; }
    return lo;
}

// K6: merge-join query. Block = (1024-query chunk, offset k). Window of skeys staged
// in LDS via interpolation guess; per-thread LDS binary search; global-search fallback.
__global__ __launch_bounds__(256) void k_qmerge(const int* __restrict__ skeys,
                                                const int* __restrict__ sorder,
                                                const int* __restrict__ offs,
                                                int* __restrict__ paircnt,
                                                int* __restrict__ pairs, int N) {
    int nch = (N + QCHUNK - 1) / QCHUNK;
    int c = blockIdx.x % nch;
    int k = blockIdx.x / nch;                // 0..12 (center handled densely)
    int i0 = c * QCHUNK;
    int iend = min(i0 + QCHUNK, N);
    int ok = offs[3 * k] * 1048576 + offs[3 * k + 1] * 1024 + offs[3 * k + 2];

    __shared__ int sw[WCAP];
    int qmin = skeys[i0] + ok;
    int qmax = skeys[iend - 1] + ok;
    long long glo = ((long long)qmin * N) >> 30;   // keys ~uniform over [0, 2^30)
    long long ghi = ((long long)qmax * N) >> 30;
    int wlo = (int)max(0LL, glo - WPAD);
    int whi = (int)min((long long)N, ghi + WPAD + 1);
    if (whi - wlo > WCAP) whi = wlo + WCAP;        // clamp; fallback covers the rest
    int wn = whi - wlo;
    for (int t = threadIdx.x; t < wn; t += 256) sw[t] = skeys[wlo + t];
    __syncthreads();
    int wfirst = (wn > 0) ? sw[0] : 0;
    int wlast  = (wn > 0) ? sw[wn - 1] : 0;

#pragma unroll
    for (int u = 0; u < QCHUNK / 256; ++u) {
        int i = i0 + u * 256 + threadIdx.x;
        if (i >= iend) continue;
        int q = skeys[i] + ok;
        int j = -1;
        if (wn > 0 && q == wfirst) {
            j = wlo;                                   // unique keys -> exact
        } else if (wn > 0 && q > wfirst && q <= wlast) {
            int lo = 0, hi = wn;
            while (lo < hi) { int mid = (lo + hi) >> 1; if (sw[mid] < q) lo = mid + 1; else hi = mid; }
            if (sw[lo] == q) j = wlo + lo;
        } else if ((wn > 0 && q < wfirst && wlo == 0) ||
                   (wn > 0 && q > wlast && whi == N)) {
            j = -1;                                    // provably absent
        } else {
            int pos = lower_bound_g(skeys, N, q);      // rare fallback, always correct
            if (pos < N && skeys[pos] == q) j = pos;
        }
        if (j >= 0) {
            int idx = atomicAdd(paircnt, 2);
            if (idx + 1 < PAIR_CAP) {
                // out[i] += F[sorder[j]] @ W[k];  out[j] += F[sorder[i]] @ W[26-k]
                pairs[3 * idx + 0] = i;
                pairs[3 * idx + 1] = sorder[j];
                pairs[3 * idx + 2] = k;
                pairs[3 * idx + 3] = j;
                pairs[3 * idx + 4] = sorder[i];
                pairs[3 * idx + 5] = 26 - k;
            }
        }
    }
}

// K7: sparse pairs — one wave per pair, fp32 shuffle-dot, atomic accumulate.
__global__ void k_pairs(const float* __restrict__ feat, const float* __restrict__ kern,
                        const int* __restrict__ pairs, const int* __restrict__ paircnt,
                        float* __restrict__ out) {
    int gtid = blockIdx.x * blockDim.x + threadIdx.x;
    int wid = gtid >> 6, lane = gtid & 63;
    int nw = (gridDim.x * blockDim.x) >> 6;
    int cnt = *paircnt;
    if (cnt > PAIR_CAP) cnt = PAIR_CAP;
    for (int p = wid; p < cnt; p += nw) {
        int dst = pairs[3 * p], src = pairs[3 * p + 1], wk = pairs[3 * p + 2];
        float f = feat[(size_t)src * 64 + lane];
        const float* W = kern + wk * 4096;
        float acc = 0.f;
#pragma unroll
        for (int c = 0; c < 64; ++c)
            acc += __shfl(f, c, 64) * W[c * 64 + lane];
        atomicAdd(&out[(size_t)dst * 64 + lane], acc);
    }
}

extern "C" void kernel_launch(void* const* d_in, const int* in_sizes, int n_in,
                              void* d_out, int out_size, void* d_ws, size_t ws_size,
                              hipStream_t stream) {
    const float* feat   = (const float*)d_in[0];
    const float* kern   = (const float*)d_in[1];
    const int*   coords = (const int*)d_in[2];
    const int*   offs   = (const int*)d_in[3];
    float* out = (float*)d_out;
    int N = in_sizes[0] / 64;

    // ---- workspace layout (256B-aligned slabs) ----
    char* w = (char*)d_ws;
    auto alloc = [&](size_t bytes) { char* p = w; w += (bytes + 255) & ~(size_t)255; return p; };
    int* keys    = (int*)alloc((size_t)N * 4);
    u64* sortbuf = (u64*)alloc((size_t)N * 8);
    int* skeys   = (int*)alloc((size_t)N * 4);
    int* sorder  = (int*)alloc((size_t)N * 4);
    int* rank_   = (int*)alloc((size_t)N * 4);
    int* hist    = (int*)alloc(4096 * 4);        // contiguous: hist, cnt, paircnt
    int* cnt     = (int*)alloc(4096 * 4);
    int* paircnt = (int*)alloc(256);
    int* base    = (int*)alloc(4097 * 4);
    int* pairs   = (int*)alloc((size_t)PAIR_CAP * 12);
    bf16_t* wf   = (bf16_t*)alloc(4096 * 2);

    // zero hist+cnt+paircnt (contiguous slabs)
    hipMemsetAsync(hist, 0, 4096 * 4 + 4096 * 4 + 256, stream);

    int nb = (N + 255) / 256;
    int nch = (N + QCHUNK - 1) / QCHUNK;
    k_phase1  <<<nb + 16, 256, 0, stream>>>(coords, kern, keys, hist, wf, N, nb);
    k_prefix  <<<1, 256, 0, stream>>>(hist, base);
    k_build   <<<nb, 256, 0, stream>>>(keys, base, cnt, sortbuf, N);
    k_sortrank<<<4096, 256, 0, stream>>>(base, sortbuf, skeys, sorder, rank_);
    k_gemm    <<<(N + 63) / 64, 256, 0, stream>>>(feat, wf, rank_, out, N);
    k_qmerge  <<<nch * 13, 256, 0, stream>>>(skeys, sorder, offs, paircnt, pairs, N);
    k_pairs   <<<256, 256, 0, stream>>>(feat, kern, pairs, paircnt, out);
}